// Round 5
// baseline (253.034 us; speedup 1.0000x reference)
//
#include <hip/hip_runtime.h>
#include <hip/hip_bf16.h>
#include <math.h>

#define BB 2
#define SS 4096
#define DD 512
#define HH 8
#define HD 64
#define MSD (BB*SS*DD)          // 4194304 elements per matrix
#define WSZ (DD*DD)             // 262144 elements per weight

// ws layout (ushort elements):
//   Qb @ 0      [bh][s][hd]  (pre-scaled by log2e/sqrt(512))
//   Kb @ MSD    [bh][s][hd]
//   Vt @ 2*MSD  [bh][hd][s]
//   xb @ 4*MSD  [m][k]
//   Wb @ 5*MSD  3 x [n][k]
#define XOFF (4*(size_t)MSD)
#define WOFF (5*(size_t)MSD)

typedef __attribute__((ext_vector_type(8))) short bf16x8;
typedef __attribute__((ext_vector_type(4))) float f32x4;

__device__ __forceinline__ unsigned short f2bf(float f) {
    unsigned int u = __float_as_uint(f);
    u += 0x7fff + ((u >> 16) & 1);
    return (unsigned short)(u >> 16);
}
__device__ __forceinline__ unsigned int pk2bf(float a, float b) {
    __hip_bfloat162 h = __float22bfloat162_rn(make_float2(a, b));
    union { __hip_bfloat162 h2; unsigned int u; } cv; cv.h2 = h;
    return cv.u;   // low 16 = a, high 16 = b
}

#define GLD16(gsrc, ldst) \
    __builtin_amdgcn_global_load_lds((const __attribute__((address_space(1))) unsigned int*)(gsrc), \
                                     (__attribute__((address_space(3))) unsigned int*)(ldst), 16, 0, 0)

// ---------------------------------------------------------------------------
// fp32 -> bf16 convert: x (MSD els) and Wq|Wk|Wv (3*WSZ els). 8 els/thread.
// ---------------------------------------------------------------------------
__global__ __launch_bounds__(256)
void convert_bf16(const float* __restrict__ x,
                  const float* __restrict__ Wq, const float* __restrict__ Wk,
                  const float* __restrict__ Wv, unsigned short* __restrict__ ws) {
    const int i8 = blockIdx.x*256 + threadIdx.x;
    const float* src; unsigned short* dst; size_t off;
    if (i8 < MSD/8) {
        src = x; dst = ws + XOFF; off = (size_t)i8 * 8;
    } else {
        size_t o = ((size_t)i8 - MSD/8) * 8;
        int wsel = (int)(o / WSZ);
        src = (wsel == 0) ? Wq : (wsel == 1) ? Wk : Wv;
        dst = ws + WOFF + (size_t)wsel*WSZ;
        off = o % WSZ;
    }
    float4 a = *(const float4*)&src[off];
    float4 b = *(const float4*)&src[off+4];
    unsigned short r[8] = { f2bf(a.x), f2bf(a.y), f2bf(a.z), f2bf(a.w),
                            f2bf(b.x), f2bf(b.y), f2bf(b.z), f2bf(b.w) };
    *(bf16x8*)&dst[off] = *(const bf16x8*)r;
}

// ---------------------------------------------------------------------------
// QKV GEMM, bf16 MFMA: C = X @ W^T + b. 128x128 tile, BK=64, 4 waves (2x2).
// z<2 (Q,K): OPERAND-SWAPPED mfma (A=W, B=X) -> lane holds C^T[n 4-consec][m]
//   -> packed uint2 stores along hd into [bh][s][hd]. Q scaled by log2e/sqrt(512).
// z=2 (V): normal order, packed uint2 stores along s into V^T [bh][hd][s].
// grid (4, 64, 3), block 256.
// ---------------------------------------------------------------------------
__global__ __launch_bounds__(256)
void qkv_mfma(const float* __restrict__ bq, const float* __restrict__ bk,
              const float* __restrict__ bv, unsigned short* __restrict__ ws) {
    const int z = blockIdx.z;
    const unsigned short* Xb = ws + XOFF;
    const unsigned short* Wb = ws + WOFF + (size_t)z*WSZ;
    const float* bias = (z == 0) ? bq : (z == 1) ? bk : bv;
    unsigned short* dst = ws + (size_t)z*MSD;

    __shared__ __align__(16) unsigned short As[128*64];
    __shared__ __align__(16) unsigned short Bs[128*64];

    const int tid  = threadIdx.x;
    const int w    = tid >> 6, l = tid & 63;
    const int quad = l >> 4,  r16 = l & 15;
    const int wy   = w >> 1,  wx  = w & 1;
    const int m0   = blockIdx.y * 128;
    const int n0   = blockIdx.x * 128;

    const int srow   = l >> 3;
    const int schunk = (l & 7) ^ srow;

    f32x4 acc[4][4];
    #pragma unroll
    for (int i = 0; i < 4; ++i)
        #pragma unroll
        for (int j = 0; j < 4; ++j) acc[i][j] = (f32x4){0.f,0.f,0.f,0.f};

    for (int k0 = 0; k0 < DD; k0 += 64) {
        __syncthreads();
        #pragma unroll
        for (int u = 0; u < 4; ++u) {
            const int r0 = w*32 + u*8;
            GLD16(&Xb[(size_t)(m0 + r0 + srow)*DD + k0 + schunk*8], &As[r0*64]);
            GLD16(&Wb[(size_t)(n0 + r0 + srow)*DD + k0 + schunk*8], &Bs[r0*64]);
        }
        __syncthreads();
        #pragma unroll
        for (int kc = 0; kc < 2; ++kc) {
            bf16x8 a[4], b[4];
            #pragma unroll
            for (int i = 0; i < 4; ++i) {
                const int mr = wy*64 + i*16 + r16;
                a[i] = *(const bf16x8*)&As[mr*64 + (((kc*4+quad) ^ (mr&7))*8)];
                const int nr = wx*64 + i*16 + r16;
                b[i] = *(const bf16x8*)&Bs[nr*64 + (((kc*4+quad) ^ (nr&7))*8)];
            }
            #pragma unroll
            for (int i = 0; i < 4; ++i)
                #pragma unroll
                for (int j = 0; j < 4; ++j) {
                    if (z == 2)
                        acc[i][j] = __builtin_amdgcn_mfma_f32_16x16x32_bf16(a[i], b[j], acc[i][j], 0, 0, 0);
                    else
                        acc[i][j] = __builtin_amdgcn_mfma_f32_16x16x32_bf16(b[j], a[i], acc[i][j], 0, 0, 0);
                }
        }
    }

    const float qscale = 0.04419417382415922f * 1.4426950408889634f; // 1/sqrt(512)*log2e
    if (z == 2) {
        // lane holds C[m = i*16+quad*4+reg][n = j*16+r16]; V^T wants [hd=n][s=m]
        #pragma unroll
        for (int j = 0; j < 4; ++j) {
            const int n = n0 + wx*64 + j*16 + r16;
            const float bz = bias[n];
            const int h = n >> 6, hd = n & 63;
            #pragma unroll
            for (int i = 0; i < 4; ++i) {
                const int mbase = m0 + wy*64 + i*16 + quad*4;
                const int b_ = mbase >> 12, s_ = mbase & (SS-1);
                unsigned short r4[4];
                #pragma unroll
                for (int reg = 0; reg < 4; ++reg)
                    r4[reg] = f2bf(acc[i][j][reg] + bz);
                *(uint2*)&dst[((size_t)(b_*HH + h)*HD + hd)*SS + s_] = *(const uint2*)r4;
            }
        }
    } else {
        // lane holds C^T[n = j*16+quad*4+reg][m = i*16+r16]; [s=m][hd=n] packed
        #pragma unroll
        for (int j = 0; j < 4; ++j) {
            const int nb = n0 + wx*64 + j*16 + quad*4;
            const int h = nb >> 6, hd = nb & 63;
            const float4 bz4 = *(const float4*)&bias[nb];
            #pragma unroll
            for (int i = 0; i < 4; ++i) {
                const int m  = m0 + wy*64 + i*16 + r16;
                const int b_ = m >> 12, s_ = m & (SS-1);
                float v0 = acc[i][j][0] + bz4.x;
                float v1 = acc[i][j][1] + bz4.y;
                float v2 = acc[i][j][2] + bz4.z;
                float v3 = acc[i][j][3] + bz4.w;
                if (z == 0) { v0 *= qscale; v1 *= qscale; v2 *= qscale; v3 *= qscale; }
                unsigned short r4[4] = { f2bf(v0), f2bf(v1), f2bf(v2), f2bf(v3) };
                *(uint2*)&dst[((size_t)(b_*HH + h)*SS + s_)*HD + hd] = *(const uint2*)r4;
            }
        }
    }
}

// ---------------------------------------------------------------------------
// Barrier-free MFMA flash attention. One wave per block, 64 q per wave.
// S^T = K Q^T with K/V^T A-fragments loaded DIRECTLY from global (contiguous
// 16B per lane). Streaming softmax (fixed max, exp2-safe). P round-trips via
// an 8KB XOR-swizzled per-block LDS buffer (ds_write_b64 / ds_read_b128).
// grid 1024 (bh in low 4 bits for XCD L2 locality; heavy q-chunks first).
// ---------------------------------------------------------------------------
__global__ __launch_bounds__(64, 1)
void attn_mfma(const unsigned short* __restrict__ ws, float* __restrict__ out) {
    const int bh   = blockIdx.x & 15;
    const int qc   = 63 - (blockIdx.x >> 4);    // heavy-first
    const int qlo  = qc * 64;
    const int l    = threadIdx.x;
    const int quad = l >> 4, r16 = l & 15;

    const unsigned short* Qg  = ws;             // pre-scaled
    const unsigned short* Kg  = ws + (size_t)MSD;
    const unsigned short* Vtg = ws + 2*(size_t)MSD;

    __shared__ __align__(16) unsigned short Ps[64*64];

    // Q B-frags: lane holds Q[q = qlo+nt*16+r16][d = kc*32+quad*8 ..+7]
    bf16x8 bqf[4][2];
    #pragma unroll
    for (int nt = 0; nt < 4; ++nt)
        #pragma unroll
        for (int kc = 0; kc < 2; ++kc)
            bqf[nt][kc] = *(const bf16x8*)&Qg[((size_t)bh*SS + qlo + nt*16 + r16)*HD + kc*32 + quad*8];

    f32x4 od[4][4];   // O^T accum: [mt -> d][nt -> q]
    #pragma unroll
    for (int mt = 0; mt < 4; ++mt)
        #pragma unroll
        for (int nt = 0; nt < 4; ++nt) od[mt][nt] = (f32x4){0.f,0.f,0.f,0.f};
    float lsum[4] = {0.f, 0.f, 0.f, 0.f};

    const size_t kbase = (size_t)bh*SS*HD;
    const size_t vbase = (size_t)bh*HD*SS;

    for (int jb = 0; jb <= qlo; jb += 64) {
        // direct-global A-fragments (16B contiguous per lane)
        bf16x8 kf[4][2], vf[4][2];
        #pragma unroll
        for (int mt = 0; mt < 4; ++mt)
            #pragma unroll
            for (int kc = 0; kc < 2; ++kc) {
                kf[mt][kc] = *(const bf16x8*)&Kg [kbase + (size_t)(jb + mt*16 + r16)*HD + kc*32 + quad*8];
                vf[mt][kc] = *(const bf16x8*)&Vtg[vbase + (size_t)(mt*16 + r16)*SS + jb + kc*32 + quad*8];
            }

        const bool diag = (jb == qlo);

        // ---- per key-16-tile: S^T slab -> exp2 -> pack -> LDS (streaming)
        #pragma unroll
        for (int mt = 0; mt < 4; ++mt) {
            f32x4 z[4];
            #pragma unroll
            for (int nt = 0; nt < 4; ++nt) z[nt] = (f32x4){0.f,0.f,0.f,0.f};
            #pragma unroll
            for (int kc = 0; kc < 2; ++kc)
                #pragma unroll
                for (int nt = 0; nt < 4; ++nt)
                    z[nt] = __builtin_amdgcn_mfma_f32_16x16x32_bf16(kf[mt][kc], bqf[nt][kc], z[nt], 0, 0, 0);

            if (diag) {   // causal: key_local mt*16+quad*4+reg > q_local nt*16+r16
                #pragma unroll
                for (int nt = 0; nt < 4; ++nt)
                    #pragma unroll
                    for (int reg = 0; reg < 4; ++reg)
                        if (mt*16 + quad*4 + reg > nt*16 + r16)
                            z[nt][reg] = -1e30f;
            }

            const int sw = ((mt*2 + (quad >> 1)) ^ (r16 & 7)) * 8 + (quad & 1)*4;
            #pragma unroll
            for (int nt = 0; nt < 4; ++nt) {
                #pragma unroll
                for (int reg = 0; reg < 4; ++reg) {
                    z[nt][reg] = exp2f(z[nt][reg]);
                    lsum[nt] += z[nt][reg];
                }
                uint2 pk;
                pk.x = pk2bf(z[nt][0], z[nt][1]);
                pk.y = pk2bf(z[nt][2], z[nt][3]);
                *(uint2*)&Ps[(nt*16 + r16)*64 + sw] = pk;   // ds_write_b64
            }
        }

        asm volatile("s_waitcnt lgkmcnt(0)" ::: "memory");  // wave-private round-trip

        // ---- O^T += V^T P^T
        #pragma unroll
        for (int kc = 0; kc < 2; ++kc)
            #pragma unroll
            for (int nt = 0; nt < 4; ++nt) {
                bf16x8 pf = *(const bf16x8*)&Ps[(nt*16 + r16)*64 + (((kc*4 + quad) ^ (r16 & 7))*8)];
                #pragma unroll
                for (int mt = 0; mt < 4; ++mt)
                    od[mt][nt] = __builtin_amdgcn_mfma_f32_16x16x32_bf16(vf[mt][kc], pf, od[mt][nt], 0, 0, 0);
            }
    }

    // ---- l: sum the 4 quad-partials per q
    #pragma unroll
    for (int nt = 0; nt < 4; ++nt) {
        lsum[nt] += __shfl_xor(lsum[nt], 16);
        lsum[nt] += __shfl_xor(lsum[nt], 32);
    }

    const int b_ = bh >> 3, h = bh & 7;
    #pragma unroll
    for (int nt = 0; nt < 4; ++nt) {
        const float inv = 1.0f / lsum[nt];
        const int q = qlo + nt*16 + r16;
        float* op = out + ((size_t)(b_*SS + q))*DD + h*HD;
        #pragma unroll
        for (int mt = 0; mt < 4; ++mt) {
            float4 t;
            t.x = od[mt][nt][0]*inv; t.y = od[mt][nt][1]*inv;
            t.z = od[mt][nt][2]*inv; t.w = od[mt][nt][3]*inv;
            *(float4*)&op[mt*16 + quad*4] = t;
        }
    }
}

extern "C" void kernel_launch(void* const* d_in, const int* in_sizes, int n_in,
                              void* d_out, int out_size, void* d_ws, size_t ws_size,
                              hipStream_t stream) {
    const float* x  = (const float*)d_in[0];
    const float* Wq = (const float*)d_in[1];
    const float* bq = (const float*)d_in[2];
    const float* Wk = (const float*)d_in[3];
    const float* bk = (const float*)d_in[4];
    const float* Wv = (const float*)d_in[5];
    const float* bv = (const float*)d_in[6];
    float* out = (float*)d_out;
    unsigned short* ws = (unsigned short*)d_ws;

    const int nconv = (MSD/8 + 3*WSZ/8 + 255) / 256;
    convert_bf16<<<nconv, 256, 0, stream>>>(x, Wq, Wk, Wv, ws);

    dim3 ggrid(DD/128, (BB*SS)/128, 3);           // (4, 64, 3)
    qkv_mfma<<<ggrid, 256, 0, stream>>>(bq, bk, bv, ws);

    attn_mfma<<<1024, 64, 0, stream>>>(ws, out);
}